// Round 1
// baseline (262.464 us; speedup 1.0000x reference)
//
#include <hip/hip_runtime.h>
#include <stdint.h>

#define HH 128
#define WW 128
#define CIN 256
#define OCH 256
#define HW (HH*WW)

typedef __attribute__((ext_vector_type(8))) short bf16x8;
typedef __attribute__((ext_vector_type(16))) float f32x16;

static __device__ __forceinline__ uint16_t f2bf(float f) {
  uint32_t u = __builtin_bit_cast(uint32_t, f);
  u += 0x7FFFu + ((u >> 16) & 1u);
  return (uint16_t)(u >> 16);
}
static __device__ __forceinline__ float bf2f(uint16_t h) {
  uint32_t u = ((uint32_t)h) << 16;
  return __builtin_bit_cast(float, u);
}

// ---------------- pack w -> bf16 [k][c8][oc][8] ----------------
__global__ void pack_w_kernel(const float* __restrict__ w, uint16_t* __restrict__ wpk) {
  int i = blockIdx.x * 256 + threadIdx.x;      // < 9*32*256*8 = 589824
  int ci = i & 7;
  int oc = (i >> 3) & 255;
  int c8 = (i >> 11) & 31;
  int k  = i >> 16;
  int c = c8 * 8 + ci;
  wpk[i] = f2bf(w[(oc * 256 + c) * 9 + k]);
}

// ---------------- x NCHW f32 -> NHWC bf16 ----------------
__global__ void transpose_kernel(const float* __restrict__ x, uint32_t* __restrict__ xt) {
  __shared__ float tile[64][65];
  int wg = blockIdx.x;            // 2048
  int b  = wg >> 10;
  int r  = wg & 1023;
  int pt = r >> 2, ct = r & 3;
  int p0 = pt * 64, c0 = ct * 64;
  int t = threadIdx.x;
#pragma unroll
  for (int i = 0; i < 16; ++i) {
    int cl = i * 4 + (t >> 6);
    tile[cl][t & 63] = x[(size_t)(b * CIN + c0 + cl) * HW + p0 + (t & 63)];
  }
  __syncthreads();
  int c2 = t & 31, pr = t >> 5;
#pragma unroll
  for (int i = 0; i < 8; ++i) {
    int pl = i * 8 + pr;
    uint32_t lo = f2bf(tile[2 * c2][pl]);
    uint32_t hi = f2bf(tile[2 * c2 + 1][pl]);
    xt[(size_t)(b * HW + p0 + pl) * 128 + (c0 >> 1) + c2] = lo | (hi << 16);
  }
}

// ---------------- offset conv: off (B,256,H,W) -> per px 9*(dy,dx,mask) ----------------
__global__ void offc_kernel(const float* __restrict__ off, const float* __restrict__ w_off,
                            const float* __restrict__ b_off, float* __restrict__ offs) {
  __shared__ float wl[27 * 256];
  int t = threadIdx.x;            // 64
  for (int r = t; r < 27 * 256; r += 64) wl[r] = w_off[r];
  __syncthreads();
  int px = blockIdx.x * 64 + t;   // < 32768
  int b = px >> 14, yx = px & 16383;
  float acc[27];
#pragma unroll
  for (int j = 0; j < 27; ++j) acc[j] = b_off[j];
  const float* op = off + (size_t)b * CIN * HW + yx;
  for (int c = 0; c < 256; c += 4) {
    float v0 = op[(size_t)(c + 0) * HW];
    float v1 = op[(size_t)(c + 1) * HW];
    float v2 = op[(size_t)(c + 2) * HW];
    float v3 = op[(size_t)(c + 3) * HW];
#pragma unroll
    for (int j = 0; j < 27; ++j) {
      acc[j] = fmaf(wl[j * 256 + c + 0], v0, acc[j]);
      acc[j] = fmaf(wl[j * 256 + c + 1], v1, acc[j]);
      acc[j] = fmaf(wl[j * 256 + c + 2], v2, acc[j]);
      acc[j] = fmaf(wl[j * 256 + c + 3], v3, acc[j]);
    }
  }
  float* o = offs + (size_t)px * 27;
#pragma unroll
  for (int k = 0; k < 9; ++k) {
    o[k * 3 + 0] = acc[2 * k];
    o[k * 3 + 1] = acc[2 * k + 1];
    o[k * 3 + 2] = 1.f / (1.f + expf(-acc[18 + k]));
  }
}

// ---------------- fused gather + MFMA GEMM ----------------
__global__ __launch_bounds__(256) void main_kernel(
    const uint32_t* __restrict__ xt, const float* __restrict__ offs,
    const uint16_t* __restrict__ wpk, const float* __restrict__ bias,
    float* __restrict__ out) {
  __shared__ struct __align__(16) { unsigned char A[64 * 512]; float offs_l[64 * 27]; } sm;

  int wg = blockIdx.x;                  // 512
  wg = (wg & 7) * 64 + (wg >> 3);       // XCD-aware swizzle (512 % 8 == 0, bijective)
  int b = wg >> 8;
  int tile = wg & 255;
  int y0 = (tile >> 3) * 4, x0 = (tile & 7) * 16;

  int tid = threadIdx.x;
  int lane = tid & 63;
  int wv = tid >> 6;                    // N-group 0..3
  int l31 = lane & 31, g = lane >> 5;

  // preload offsets for the 64-px tile
  {
    int base = b * HW + y0 * WW + x0;
    for (int r = tid; r < 64 * 27; r += 256) {
      int pyl = r / 432;                // 432 = 16*27
      int rem = r - pyl * 432;
      sm.offs_l[pyl * 432 + rem] = offs[(size_t)(base + pyl * WW) * 27 + rem];
    }
  }
  f32x16 acc[2][2] = {};
  __syncthreads();

  const int hw = tid >> 5;              // half-wave id 0..7
  const int j = tid & 31;               // channel-octet lane
  const uint4* xt4 = (const uint4*)xt;
  const uint4* wp4 = (const uint4*)wpk;
  const int pb = b * HW;
  const uint32_t rswz = (uint32_t)((lane & 7) << 4);

#pragma unroll 1
  for (int k = 0; k < 9; ++k) {
    int kh = k / 3 - 1, kw = k % 3 - 1;
    // ---- gather A[64 px][256 c] (bf16, mask folded in) ----
#pragma unroll 2
    for (int i = 0; i < 8; ++i) {
      int px = hw * 8 + i;
      int py = px >> 4, pxx = px & 15;
      float dy = sm.offs_l[px * 27 + k * 3 + 0];
      float dx = sm.offs_l[px * 27 + k * 3 + 1];
      float m  = sm.offs_l[px * 27 + k * 3 + 2];
      float ys = (float)(y0 + py + kh) + dy;
      float xs = (float)(x0 + pxx + kw) + dx;
      float yf = floorf(ys), xf = floorf(xs);
      float wy1 = ys - yf, wx1 = xs - xf;
      float wy0 = 1.f - wy1, wx0 = 1.f - wx1;
      int iy0 = (int)yf, ix0 = (int)xf;
      int iy1 = iy0 + 1, ix1 = ix0 + 1;
      float vy0 = (iy0 >= 0 && iy0 < HH) ? 1.f : 0.f;
      float vy1 = (iy1 >= 0 && iy1 < HH) ? 1.f : 0.f;
      float vx0 = (ix0 >= 0 && ix0 < WW) ? 1.f : 0.f;
      float vx1 = (ix1 >= 0 && ix1 < WW) ? 1.f : 0.f;
      float w00 = wy0 * wx0 * vy0 * vx0 * m;
      float w01 = wy0 * wx1 * vy0 * vx1 * m;
      float w10 = wy1 * wx0 * vy1 * vx0 * m;
      float w11 = wy1 * wx1 * vy1 * vx1 * m;
      int cy0 = iy0 < 0 ? 0 : (iy0 > HH - 1 ? HH - 1 : iy0);
      int cy1 = iy1 < 0 ? 0 : (iy1 > HH - 1 ? HH - 1 : iy1);
      int cx0 = ix0 < 0 ? 0 : (ix0 > WW - 1 ? WW - 1 : ix0);
      int cx1 = ix1 < 0 ? 0 : (ix1 > WW - 1 ? WW - 1 : ix1);
      uint4 q00 = xt4[(size_t)(pb + cy0 * WW + cx0) * 32 + j];
      uint4 q01 = xt4[(size_t)(pb + cy0 * WW + cx1) * 32 + j];
      uint4 q10 = xt4[(size_t)(pb + cy1 * WW + cx0) * 32 + j];
      uint4 q11 = xt4[(size_t)(pb + cy1 * WW + cx1) * 32 + j];
      uint32_t u00[4] = {q00.x, q00.y, q00.z, q00.w};
      uint32_t u01[4] = {q01.x, q01.y, q01.z, q01.w};
      uint32_t u10[4] = {q10.x, q10.y, q10.z, q10.w};
      uint32_t u11[4] = {q11.x, q11.y, q11.z, q11.w};
      uint32_t ow[4];
#pragma unroll
      for (int q = 0; q < 4; ++q) {
        float lo = w00 * bf2f((uint16_t)u00[q]) + w01 * bf2f((uint16_t)u01[q])
                 + w10 * bf2f((uint16_t)u10[q]) + w11 * bf2f((uint16_t)u11[q]);
        float hi = w00 * bf2f((uint16_t)(u00[q] >> 16)) + w01 * bf2f((uint16_t)(u01[q] >> 16))
                 + w10 * bf2f((uint16_t)(u10[q] >> 16)) + w11 * bf2f((uint16_t)(u11[q] >> 16));
        ow[q] = (uint32_t)f2bf(lo) | ((uint32_t)f2bf(hi) << 16);
      }
      *(uint4*)(&sm.A[px * 512 + ((j * 16) ^ ((px & 7) << 4))]) =
          make_uint4(ow[0], ow[1], ow[2], ow[3]);
    }
    __syncthreads();   // A ready

    // ---- MFMA over c (K=256 per tap) ----
    int oc0 = wv * 64 + l31;
#pragma unroll
    for (int chunk = 0; chunk < 8; ++chunk) {
#pragma unroll
      for (int cs = 0; cs < 2; ++cs) {
        int boff = (chunk * 64 + cs * 32 + g * 16) ^ rswz;
        uint4 ua0 = *(const uint4*)(&sm.A[l31 * 512 + boff]);
        uint4 ua1 = *(const uint4*)(&sm.A[(l31 + 32) * 512 + boff]);
        int bidx = k * 8192 + (chunk * 4 + cs * 2 + g) * 256;
        uint4 ub0 = wp4[bidx + oc0];
        uint4 ub1 = wp4[bidx + oc0 + 32];
        bf16x8 a0 = __builtin_bit_cast(bf16x8, ua0);
        bf16x8 a1 = __builtin_bit_cast(bf16x8, ua1);
        bf16x8 b0 = __builtin_bit_cast(bf16x8, ub0);
        bf16x8 b1 = __builtin_bit_cast(bf16x8, ub1);
        acc[0][0] = __builtin_amdgcn_mfma_f32_32x32x16_bf16(a0, b0, acc[0][0], 0, 0, 0);
        acc[0][1] = __builtin_amdgcn_mfma_f32_32x32x16_bf16(a0, b1, acc[0][1], 0, 0, 0);
        acc[1][0] = __builtin_amdgcn_mfma_f32_32x32x16_bf16(a1, b0, acc[1][0], 0, 0, 0);
        acc[1][1] = __builtin_amdgcn_mfma_f32_32x32x16_bf16(a1, b1, acc[1][1], 0, 0, 0);
      }
    }
    __syncthreads();   // before next gather overwrites A
  }

  // ---- epilogue: bias + relu, scatter to NCHW out ----
  float bias0 = bias[wv * 64 + l31];
  float bias1 = bias[wv * 64 + 32 + l31];
#pragma unroll
  for (int tm = 0; tm < 2; ++tm) {
#pragma unroll
    for (int tn = 0; tn < 2; ++tn) {
      int oc = wv * 64 + tn * 32 + l31;
      float bv = tn ? bias1 : bias0;
#pragma unroll
      for (int r = 0; r < 16; ++r) {
        int row = (r & 3) + 8 * (r >> 2) + 4 * g + 32 * tm;
        int y = y0 + (row >> 4), x = x0 + (row & 15);
        float v = acc[tm][tn][r] + bv;
        out[((size_t)(b * OCH + oc) << 14) + (y << 7) + x] = fmaxf(v, 0.f);
      }
    }
  }
}

extern "C" void kernel_launch(void* const* d_in, const int* in_sizes, int n_in,
                              void* d_out, int out_size, void* d_ws, size_t ws_size,
                              hipStream_t stream) {
  const float* x     = (const float*)d_in[0];
  const float* off   = (const float*)d_in[1];
  const float* w_off = (const float*)d_in[2];
  const float* b_off = (const float*)d_in[3];
  const float* w     = (const float*)d_in[4];
  const float* bias  = (const float*)d_in[5];
  float* out = (float*)d_out;
  char* ws = (char*)d_ws;
  uint32_t* xt   = (uint32_t*)ws;                              // 16 MB  (NHWC bf16)
  float*    offs = (float*)(ws + 16777216);                    // 3.54 MB (px*27)
  uint16_t* wpk  = (uint16_t*)(ws + 16777216 + 3538944);       // 1.18 MB (packed w)

  pack_w_kernel<<<2304, 256, 0, stream>>>(w, wpk);
  transpose_kernel<<<2048, 256, 0, stream>>>(x, xt);
  offc_kernel<<<512, 64, 0, stream>>>(off, w_off, b_off, offs);
  main_kernel<<<512, 256, 0, stream>>>(xt, offs, wpk, bias, out);
}